// Round 4
// baseline (428.940 us; speedup 1.0000x reference)
//
#include <hip/hip_runtime.h>

#define B_   32
#define D_   256
#define HW_  1024
#define N_   32768
#define K_   1024
#define DHW  (D_ * HW_)      // 262144
#define MARGIN 0.3f

typedef __attribute__((ext_vector_type(8)))  short bf16x8;
typedef __attribute__((ext_vector_type(16))) float f32x16;

union FragU { uint4 q; bf16x8 v; };

__device__ inline uint bf16rne(float x) {
    uint ub = __float_as_uint(x);
    return (ub + 0x7fffu + ((ub >> 16) & 1u)) >> 16;
}

// ================= prep_x: x -> bf16-hi plane, token-major [token][32 g] uint4 ====
__global__ __launch_bounds__(256)
void prep_x(const float* __restrict__ x, uint4* __restrict__ xg) {
    const int tok0 = blockIdx.x * 64;
    const int b = tok0 >> 10, hw0 = tok0 & 1023;
    const int tokl = threadIdx.x & 63;
    const int gq = threadIdx.x >> 6;
    #pragma unroll
    for (int it = 0; it < 8; ++it) {
        int g = it * 4 + gq;
        const float* xp = x + (size_t)b * DHW + (size_t)(g * 8) * HW_ + hw0 + tokl;
        uint w[4];
        #pragma unroll
        for (int jj = 0; jj < 4; ++jj) {
            float e0 = xp[(size_t)(2 * jj) * HW_];
            float e1 = xp[(size_t)(2 * jj + 1) * HW_];
            w[jj] = bf16rne(e0) | (bf16rne(e1) << 16);
        }
        xg[(size_t)(tok0 + tokl) * 32 + g] = make_uint4(w[0], w[1], w[2], w[3]);
    }
}

// ================= prep_cb: codebook -> hi/lo tiled planes + csq + fp32 transpose ====
// cbt layout: [chunk 8][code 1024][8 g] uint4 ; g = p*4+gg, dpairs = chunk*16+gg*4+jj
__global__ __launch_bounds__(256)
void prep_cb(const float* __restrict__ cb, uint4* __restrict__ cbt,
             float* __restrict__ csq, float* __restrict__ cbT) {
    __shared__ uint sh[256], sl[256];
    __shared__ float rr[4];
    const int k = blockIdx.x, d = threadIdx.x;
    float v = cb[(size_t)k * D_ + d];
    uint hb = bf16rne(v);
    float hf = __uint_as_float(hb << 16);
    uint lb = bf16rne(v - hf);
    sh[d] = hb; sl[d] = lb;
    cbT[(size_t)d * K_ + k] = v;
    float s = v * v;
    #pragma unroll
    for (int off = 32; off >= 1; off >>= 1) s += __shfl_xor(s, off, 64);
    if ((d & 63) == 0) rr[d >> 6] = s;
    __syncthreads();
    if (d == 0) csq[k] = (rr[0] + rr[1]) + (rr[2] + rr[3]);
    if (d < 64) {
        int ch = d >> 3, g = d & 7;
        int p = g >> 2, gg = g & 3;
        const uint* src = p ? sl : sh;
        uint w[4];
        #pragma unroll
        for (int jj = 0; jj < 4; ++jj) {
            int dp = ch * 16 + gg * 4 + jj;
            w[jj] = src[2 * dp] | (src[2 * dp + 1] << 16);
        }
        cbt[(size_t)(ch * 1024 + k) * 8 + g] = make_uint4(w[0], w[1], w[2], w[3]);
    }
}

// ================= main: LDS-staged MFMA distances + per-lane argmin ==========
// 256 blocks x 1024 thr. Block: 128 tokens x 1024 codes. codes=A(rows, hi+lo), tokens=B(cols, hi).
__global__ __launch_bounds__(1024, 4)
void vq_main(const uint4* __restrict__ xg, const uint4* __restrict__ cbt,
             const float* __restrict__ csqg, int* __restrict__ bestk,
             int* __restrict__ rcount, int* __restrict__ rlist) {
    __shared__ uint4 TkS[4096];        // 64 KB: [token 128][32 slots], slot = g ^ (t&7)
    __shared__ uint4 CbS[2][2048];     // 2x32 KB: [code 256][8 slots], slot = g ^ (c&7)
    __shared__ float csqS[1024];       // 4 KB

    const int tid = threadIdx.x;       // 0..1023
    const int lane = tid & 63;
    const int sub = lane >> 5, l31 = lane & 31;
    const int wid = tid >> 6;          // 0..15
    const int wm = wid >> 2;           // 0..3 : code group (64 codes)
    const int wn = wid & 3;            // 0..3 : token group (32 tokens)
    const int tok0 = blockIdx.x * 128;

    csqS[tid] = csqg[tid];
    asm volatile("s_waitcnt vmcnt(0) lgkmcnt(0)" ::: "memory");

    // ---- stage tokens once: 4 x global_load_lds(16B) per thread ----
    {
        const int tloc = tid >> 5;           // + it*32
        const int slot = tid & 31;
        #pragma unroll
        for (int it = 0; it < 4; ++it) {
            int u = it * 1024 + tid;
            int t = it * 32 + tloc;
            int g = slot ^ (t & 7);          // it*32 preserves t&7
            const uint4* src = xg + (size_t)(tok0 + t) * 32 + g;
            __builtin_amdgcn_global_load_lds((const uint*)src, (uint*)&TkS[u], 16, 0, 0);
        }
    }
    // ---- code-chunk staging constants ----
    const int s_cl = tid >> 3;               // + it*128
    const int s_sl = tid & 7;

    // stage chunk 0 into buf 0
    #pragma unroll
    for (int it = 0; it < 2; ++it) {
        int u = it * 1024 + tid;
        int cl = it * 128 + s_cl;
        int g = s_sl ^ (cl & 7);
        __builtin_amdgcn_global_load_lds((const uint*)(cbt + (size_t)cl * 8 + g),
                                         (uint*)&CbS[0][u], 16, 0, 0);
    }

    f32x16 acc[2] = {};
    float v1 = 3.4e38f, v2 = 3.4e38f;
    int k1 = 0;

    int cur = 0;
    for (int cc = 0; cc < 32; ++cc) {
        asm volatile("s_barrier" ::: "memory");   // B1: reads of buf[cur^1] done
        if (cc + 1 < 32) {
            const int nct = (cc + 1) >> 3, nch = (cc + 1) & 7;
            #pragma unroll
            for (int it = 0; it < 2; ++it) {
                int u = it * 1024 + tid;
                int cl = it * 128 + s_cl;
                int g = s_sl ^ (cl & 7);
                const uint4* src = cbt + (size_t)(nch * 1024 + nct * 256 + cl) * 8 + g;
                __builtin_amdgcn_global_load_lds((const uint*)src, (uint*)&CbS[cur ^ 1][u], 16, 0, 0);
            }
            asm volatile("s_waitcnt vmcnt(2)" ::: "memory");  // buf[cur] arrived; 2 in flight
        } else {
            asm volatile("s_waitcnt vmcnt(0)" ::: "memory");
        }
        asm volatile("s_barrier" ::: "memory");   // B2: every wave's loads drained

        const int ch = cc & 7;
        #pragma unroll
        for (int ks = 0; ks < 2; ++ks) {
            FragU tf, cfh[2], cfl[2];
            {
                int t = wn * 32 + l31;
                int g32 = ch * 4 + ks * 2 + sub;
                tf.q = TkS[t * 32 + (g32 ^ (t & 7))];
            }
            #pragma unroll
            for (int f = 0; f < 2; ++f) {
                int cl = wm * 64 + f * 32 + l31;
                int gh = ks * 2 + sub;
                int gl = 4 + ks * 2 + sub;
                cfh[f].q = CbS[cur][cl * 8 + (gh ^ (cl & 7))];
                cfl[f].q = CbS[cur][cl * 8 + (gl ^ (cl & 7))];
            }
            #pragma unroll
            for (int f = 0; f < 2; ++f) {
                acc[f] = __builtin_amdgcn_mfma_f32_32x32x16_bf16(cfh[f].v, tf.v, acc[f], 0, 0, 0);
                acc[f] = __builtin_amdgcn_mfma_f32_32x32x16_bf16(cfl[f].v, tf.v, acc[f], 0, 0, 0);
            }
        }
        cur ^= 1;

        // ---- per-code-tile epilogue: scores + per-lane running top-2 ----
        if ((cc & 7) == 7) {
            const int ct = cc >> 3;
            const int cbase = ct * 256 + wm * 64 + sub * 4;
            #pragma unroll
            for (int f = 0; f < 2; ++f) {
                #pragma unroll
                for (int g8 = 0; g8 < 4; ++g8) {
                    float4 cs4 = *reinterpret_cast<const float4*>(&csqS[cbase + f * 32 + g8 * 8]);
                    const float csa[4] = {cs4.x, cs4.y, cs4.z, cs4.w};
                    #pragma unroll
                    for (int q = 0; q < 4; ++q) {
                        int code = cbase + f * 32 + g8 * 8 + q;
                        int r = g8 * 4 + q;
                        float s = fmaf(-2.f, acc[f][r], csa[q]);
                        bool c = s < v1;
                        v2 = c ? v1 : fminf(v2, s);
                        k1 = c ? code : k1;
                        v1 = c ? s : v1;
                    }
                }
            }
            const f32x16 zf = {};
            acc[0] = zf; acc[1] = zf;
        }
    }

    // ---- merge sub halves (codes interleaved across sub) ----
    {
        float ov1 = __shfl_xor(v1, 32, 64);
        float ov2 = __shfl_xor(v2, 32, 64);
        int   ok1 = __shfl_xor(k1, 32, 64);
        float nv2 = fminf(fminf(v2, ov2), fmaxf(v1, ov1));
        if (ov1 < v1 || (ov1 == v1 && ok1 < k1)) { v1 = ov1; k1 = ok1; }
        v2 = nv2;
    }
    __syncthreads();
    float* red = (float*)&CbS[0][0];   // alias: [4 wm][128 token][4]
    if (sub == 0) {
        int t = wn * 32 + l31;
        red[(wm * 128 + t) * 4 + 0] = v1;
        red[(wm * 128 + t) * 4 + 1] = v2;
        red[(wm * 128 + t) * 4 + 2] = __int_as_float(k1);
    }
    __syncthreads();
    if (tid < 128) {
        float bv1 = red[tid * 4], bv2 = red[tid * 4 + 1];
        int bk = __float_as_int(red[tid * 4 + 2]);
        #pragma unroll
        for (int m = 1; m < 4; ++m) {
            float a1 = red[(m * 128 + tid) * 4], a2 = red[(m * 128 + tid) * 4 + 1];
            int ak = __float_as_int(red[(m * 128 + tid) * 4 + 2]);
            float nv2 = fminf(fminf(bv2, a2), fmaxf(bv1, a1));
            if (a1 < bv1 || (a1 == bv1 && ak < bk)) { bv1 = a1; bk = ak; }
            bv2 = nv2;
        }
        int n = tok0 + tid;
        bestk[n] = bk;
        if (bv2 - bv1 < MARGIN) rlist[atomicAdd(rcount, 1)] = n;
    }
}

// ================= exact fp32 refine: coalesced cbT, 8-token batches, 256 blocks ====
__global__ __launch_bounds__(256)
void vq_refine(const float* __restrict__ x, const float* __restrict__ cbT,
               const float* __restrict__ csq, const int* __restrict__ rcount,
               const int* __restrict__ rlist, int* __restrict__ bestk) {
    __shared__ float xv[8][256];
    __shared__ float xsq[8];
    __shared__ float wredv[4][8];
    __shared__ int   wredk[4][8];
    const int tid = threadIdx.x;
    const int cnt = min(rcount[0], N_);
    for (int base = blockIdx.x * 8; base < cnt; base += gridDim.x * 8) {
        const int m = min(8, cnt - base);
        __syncthreads();
        for (int j = 0; j < m; ++j) {
            int n = rlist[base + j];
            int b = n >> 10, hw = n & 1023;
            xv[j][tid] = x[(size_t)b * DHW + (size_t)tid * HW_ + hw];
        }
        __syncthreads();
        {   // xsq: 8 groups of 32 lanes
            int g = tid >> 5, l = tid & 31;
            float s = 0.f;
            #pragma unroll
            for (int d8 = 0; d8 < 8; ++d8) { float v = xv[g][d8 * 32 + l]; s = fmaf(v, v, s); }
            #pragma unroll
            for (int mm = 1; mm < 32; mm <<= 1) s += __shfl_xor(s, mm, 64);
            if (l == 0) xsq[g] = s;
        }
        __syncthreads();
        float bv[8]; int bk[8];
        #pragma unroll
        for (int j = 0; j < 8; ++j) { bv[j] = 3.4e38f; bk[j] = 0; }
        #pragma unroll 1
        for (int c4 = 0; c4 < 4; ++c4) {
            const int code = c4 * 256 + tid;
            float dot[8];
            #pragma unroll
            for (int j = 0; j < 8; ++j) dot[j] = 0.f;
            for (int d = 0; d < 256; ++d) {
                float cv = cbT[(size_t)d * K_ + code];
                #pragma unroll
                for (int j = 0; j < 8; ++j) dot[j] = fmaf(cv, xv[j][d], dot[j]);
            }
            float cs = csq[code];
            #pragma unroll
            for (int j = 0; j < 8; ++j) {
                float dist = fmaf(-2.f, dot[j], xsq[j]) + cs;
                if (dist < bv[j]) { bv[j] = dist; bk[j] = code; }
            }
        }
        #pragma unroll
        for (int j = 0; j < 8; ++j) {
            if (j < m) {
                float v = bv[j]; int k = bk[j];
                #pragma unroll
                for (int mm = 1; mm < 64; mm <<= 1) {
                    float ov = __shfl_xor(v, mm, 64);
                    int   ok = __shfl_xor(k, mm, 64);
                    if (ov < v || (ov == v && ok < k)) { v = ov; k = ok; }
                }
                if ((tid & 63) == 0) { wredv[tid >> 6][j] = v; wredk[tid >> 6][j] = k; }
            }
        }
        __syncthreads();
        if (tid < m) {
            float v = wredv[0][tid]; int k = wredk[0][tid];
            #pragma unroll
            for (int q = 1; q < 4; ++q) {
                if (wredv[q][tid] < v || (wredv[q][tid] == v && wredk[q][tid] < k)) {
                    v = wredv[q][tid]; k = wredk[q][tid];
                }
            }
            bestk[rlist[base + tid]] = k;
        }
        __syncthreads();
    }
}

// ================= gather codewords, write out/idx, losses ==========
__global__ __launch_bounds__(256)
void vq_gather(const float* __restrict__ x, const float* __restrict__ cb,
               const int* __restrict__ bestk, float* __restrict__ out,
               float* __restrict__ oidx, float* __restrict__ oloss) {
    const int n0 = blockIdx.x * 64;
    const int tid = threadIdx.x;
    const int j = tid & 63, dg = tid >> 6;
    const int n = n0 + j;
    const int b = n >> 10, hw = n & 1023;
    const int k = bestk[n];
    const float* cw = cb + (size_t)k * D_;
    const size_t basex = (size_t)b * DHW + hw;
    float lsum = 0.f;
    #pragma unroll 4
    for (int d = dg * 64; d < dg * 64 + 64; ++d) {
        float q  = cw[d];
        float xvv = x[basex + (size_t)d * HW_];
        out[basex + (size_t)d * HW_] = q;
        float df = xvv - q;
        lsum = fmaf(df, df, lsum);
    }
    #pragma unroll
    for (int off = 32; off >= 1; off >>= 1) lsum += __shfl_xor(lsum, off, 64);
    if ((tid & 63) == 0) {
        float v = lsum * (1.0f / 8388608.0f);
        atomicAdd(&oloss[0], v);
        atomicAdd(&oloss[1], v);
    }
    if (tid < 64) oidx[n0 + tid] = (float)bestk[n0 + tid];
}

extern "C" void kernel_launch(void* const* d_in, const int* in_sizes, int n_in,
                              void* d_out, int out_size, void* d_ws, size_t ws_size,
                              hipStream_t stream) {
    const float* x  = (const float*)d_in[0];
    const float* cb = (const float*)d_in[1];

    float* out   = (float*)d_out;            // 8388608 floats
    float* oidx  = out + 8388608;            // 32768 floats
    float* oloss = out + 8388608 + 32768;    // 2 floats

    // d_out's first 16 MB reused as scratch for the bf16 token plane
    uint4* xg = (uint4*)d_out;               // [32768][32] uint4

    uint* wsb = (uint*)d_ws;
    uint4*  cbt   = (uint4*)wsb;             // 65536 uint4 (1 MB)
    float*  csq   = (float*)(wsb + 262144);  // 1024
    float*  cbT   = (float*)(wsb + 263168);  // 262144 (1 MB, fp32 [d][k])
    int*    bestk = (int*)  (wsb + 525312);  // 32768
    int*    rcount= (int*)  (wsb + 558080);  // 1
    int*    rlist = (int*)  (wsb + 558084);  // 32768

    hipMemsetAsync(oloss, 0, 2 * sizeof(float), stream);
    hipMemsetAsync(rcount, 0, sizeof(int), stream);

    prep_x  <<<512, 256, 0, stream>>>(x, xg);
    prep_cb <<<1024, 256, 0, stream>>>(cb, cbt, csq, cbT);
    vq_main <<<256, 1024, 0, stream>>>(xg, cbt, csq, bestk, rcount, rlist);
    vq_refine<<<256, 256, 0, stream>>>(x, cbT, csq, rcount, rlist, bestk);
    vq_gather<<<512, 256, 0, stream>>>(x, cb, bestk, out, oidx, oloss);
}

// Round 5
// 130.551 us; speedup vs baseline: 3.2856x; 3.2856x over previous
//
#include <hip/hip_runtime.h>

#define B_   32
#define D_   256
#define HW_  1024
#define N_   32768
#define K_   1024
#define DHW  (D_ * HW_)      // 262144
#define MARGIN 0.3f

typedef __attribute__((ext_vector_type(8)))  short bf16x8;
typedef __attribute__((ext_vector_type(16))) float f32x16;

union FragU { uint4 q; bf16x8 v; };

__device__ inline uint bf16rne(float x) {
    uint ub = __float_as_uint(x);
    return (ub + 0x7fffu + ((ub >> 16) & 1u)) >> 16;
}

// ================= prep_x: x -> bf16-hi plane, token-major [token][32 g] uint4 ====
__global__ __launch_bounds__(256)
void prep_x(const float* __restrict__ x, uint4* __restrict__ xg) {
    const int tok0 = blockIdx.x * 64;
    const int b = tok0 >> 10, hw0 = tok0 & 1023;
    const int tokl = threadIdx.x & 63;
    const int gq = threadIdx.x >> 6;
    #pragma unroll
    for (int it = 0; it < 8; ++it) {
        int g = it * 4 + gq;
        const float* xp = x + (size_t)b * DHW + (size_t)(g * 8) * HW_ + hw0 + tokl;
        uint w[4];
        #pragma unroll
        for (int jj = 0; jj < 4; ++jj) {
            float e0 = xp[(size_t)(2 * jj) * HW_];
            float e1 = xp[(size_t)(2 * jj + 1) * HW_];
            w[jj] = bf16rne(e0) | (bf16rne(e1) << 16);
        }
        xg[(size_t)(tok0 + tokl) * 32 + g] = make_uint4(w[0], w[1], w[2], w[3]);
    }
}

// ================= prep_cb: codebook -> hi/lo tiled planes + csq + fp32 transpose ====
__global__ __launch_bounds__(256)
void prep_cb(const float* __restrict__ cb, uint4* __restrict__ cbt,
             float* __restrict__ csq, float* __restrict__ cbT) {
    __shared__ uint sh[256], sl[256];
    __shared__ float rr[4];
    const int k = blockIdx.x, d = threadIdx.x;
    float v = cb[(size_t)k * D_ + d];
    uint hb = bf16rne(v);
    float hf = __uint_as_float(hb << 16);
    uint lb = bf16rne(v - hf);
    sh[d] = hb; sl[d] = lb;
    cbT[(size_t)d * K_ + k] = v;
    float s = v * v;
    #pragma unroll
    for (int off = 32; off >= 1; off >>= 1) s += __shfl_xor(s, off, 64);
    if ((d & 63) == 0) rr[d >> 6] = s;
    __syncthreads();
    if (d == 0) csq[k] = (rr[0] + rr[1]) + (rr[2] + rr[3]);
    if (d < 64) {
        int ch = d >> 3, g = d & 7;
        int p = g >> 2, gg = g & 3;
        const uint* src = p ? sl : sh;
        uint w[4];
        #pragma unroll
        for (int jj = 0; jj < 4; ++jj) {
            int dp = ch * 16 + gg * 4 + jj;
            w[jj] = src[2 * dp] | (src[2 * dp + 1] << 16);
        }
        cbt[(size_t)(ch * 1024 + k) * 8 + g] = make_uint4(w[0], w[1], w[2], w[3]);
    }
}

// ================= main: LDS-staged MFMA distances + per-lane argmin ==========
// 256 blocks x 512 thr. Block: 128 tokens x 1024 codes. codes=A(rows, hi+lo), tokens=B(cols, hi).
__global__ __launch_bounds__(512)
void vq_main(const uint4* __restrict__ xg, const uint4* __restrict__ cbt,
             const float* __restrict__ csqg, int* __restrict__ bestk,
             int* __restrict__ rcount, int* __restrict__ rlist,
             float* __restrict__ bdist) {
    __shared__ uint4 TkS[4096];        // 64 KB: [token 128][32 slots], slot = g ^ (t&7)
    __shared__ uint4 CbS[2][2048];     // 2x32 KB: [code 256][8 slots], slot = g ^ (c&7)
    __shared__ float csqS[1024];       // 4 KB

    const int tid = threadIdx.x;
    const int lane = tid & 63;
    const int sub = lane >> 5, l31 = lane & 31;
    const int wid = tid >> 6;
    const int wm = wid >> 1, wn = wid & 1;
    const int tok0 = blockIdx.x * 128;

    csqS[tid] = csqg[tid];
    csqS[tid + 512] = csqg[tid + 512];
    asm volatile("s_waitcnt vmcnt(0) lgkmcnt(0)" ::: "memory");

    // ---- stage tokens once: 8 x global_load_lds(16B) per thread ----
    {
        const int tloc = tid >> 5;           // + it*16
        const int slot = tid & 31;
        const int g = slot ^ (tloc & 7);     // (it*16) preserves t&7
        #pragma unroll
        for (int it = 0; it < 8; ++it) {
            int u = it * 512 + tid;
            const uint4* src = xg + (size_t)(tok0 + it * 16 + tloc) * 32 + g;
            __builtin_amdgcn_global_load_lds((const uint*)src, (uint*)&TkS[u], 16, 0, 0);
        }
    }
    // ---- code-chunk staging constants ----
    const int s_cl = tid >> 3;               // + it*64
    const int s_g = (tid & 7) ^ (s_cl & 7);  // (it*64) preserves c&7

    // stage chunk 0 into buf 0
    #pragma unroll
    for (int it = 0; it < 4; ++it) {
        int u = it * 512 + tid;
        int cl = it * 64 + s_cl;
        const uint4* src = cbt + (size_t)cl * 8 + s_g;
        __builtin_amdgcn_global_load_lds((const uint*)src, (uint*)&CbS[0][u], 16, 0, 0);
    }

    f32x16 acc[2][2] = {};
    float v1[2] = {3.4e38f, 3.4e38f}, v2[2] = {3.4e38f, 3.4e38f};
    int k1[2] = {0, 0};

    int cur = 0;
    for (int cc = 0; cc < 32; ++cc) {
        asm volatile("s_barrier" ::: "memory");   // B1: all reads of buf[cur^1] done
        if (cc + 1 < 32) {
            const int nct = (cc + 1) >> 3, nch = (cc + 1) & 7;
            #pragma unroll
            for (int it = 0; it < 4; ++it) {
                int u = it * 512 + tid;
                int cl = it * 64 + s_cl;
                const uint4* src = cbt + (size_t)(nch * 1024 + nct * 256 + cl) * 8 + s_g;
                __builtin_amdgcn_global_load_lds((const uint*)src, (uint*)&CbS[cur ^ 1][u], 16, 0, 0);
            }
            asm volatile("s_waitcnt vmcnt(4)" ::: "memory");  // buf[cur] arrived; 4 in flight
        } else {
            asm volatile("s_waitcnt vmcnt(0)" ::: "memory");
        }
        asm volatile("s_barrier" ::: "memory");   // B2: every wave's loads drained

        const int ch = cc & 7;
        #pragma unroll
        for (int ks = 0; ks < 2; ++ks) {
            FragU tf[2], cfh[2], cfl[2];
            #pragma unroll
            for (int j = 0; j < 2; ++j) {
                int t = wn * 64 + j * 32 + l31;
                int g32 = ch * 4 + ks * 2 + sub;
                tf[j].q = TkS[t * 32 + (g32 ^ (t & 7))];
            }
            #pragma unroll
            for (int f = 0; f < 2; ++f) {
                int cl = wm * 64 + f * 32 + l31;
                int gh = ks * 2 + sub;
                int gl = 4 + ks * 2 + sub;
                cfh[f].q = CbS[cur][cl * 8 + (gh ^ (cl & 7))];
                cfl[f].q = CbS[cur][cl * 8 + (gl ^ (cl & 7))];
            }
            #pragma unroll
            for (int f = 0; f < 2; ++f)
                #pragma unroll
                for (int j = 0; j < 2; ++j) {
                    acc[f][j] = __builtin_amdgcn_mfma_f32_32x32x16_bf16(cfh[f].v, tf[j].v, acc[f][j], 0, 0, 0);
                    acc[f][j] = __builtin_amdgcn_mfma_f32_32x32x16_bf16(cfl[f].v, tf[j].v, acc[f][j], 0, 0, 0);
                }
        }
        cur ^= 1;

        // ---- per-code-tile epilogue: scores + per-lane running top-2 ----
        if ((cc & 7) == 7) {
            const int ct = cc >> 3;
            const int cbase = ct * 256 + wm * 64 + sub * 4;
            #pragma unroll
            for (int f = 0; f < 2; ++f) {
                #pragma unroll
                for (int g8 = 0; g8 < 4; ++g8) {
                    float4 cs4 = *reinterpret_cast<const float4*>(&csqS[cbase + f * 32 + g8 * 8]);
                    const float csa[4] = {cs4.x, cs4.y, cs4.z, cs4.w};
                    #pragma unroll
                    for (int q = 0; q < 4; ++q) {
                        int code = cbase + f * 32 + g8 * 8 + q;
                        int r = g8 * 4 + q;
                        #pragma unroll
                        for (int j = 0; j < 2; ++j) {
                            float s = fmaf(-2.f, acc[f][j][r], csa[q]);
                            bool c = s < v1[j];
                            v2[j] = c ? v1[j] : fminf(v2[j], s);
                            k1[j] = c ? code : k1[j];
                            v1[j] = c ? s : v1[j];
                        }
                    }
                }
            }
            const f32x16 zf = {};
            #pragma unroll
            for (int f = 0; f < 2; ++f)
                #pragma unroll
                for (int j = 0; j < 2; ++j) acc[f][j] = zf;
        }
    }

    // ---- merge sub halves (codes interleaved across sub) ----
    #pragma unroll
    for (int j = 0; j < 2; ++j) {
        float ov1 = __shfl_xor(v1[j], 32, 64);
        float ov2 = __shfl_xor(v2[j], 32, 64);
        int   ok1 = __shfl_xor(k1[j], 32, 64);
        float nv2 = fminf(fminf(v2[j], ov2), fmaxf(v1[j], ov1));
        if (ov1 < v1[j] || (ov1 == v1[j] && ok1 < k1[j])) { v1[j] = ov1; k1[j] = ok1; }
        v2[j] = nv2;
    }
    __syncthreads();
    float* red = (float*)&CbS[0][0];   // alias: [4 wm][128 token][4]
    if (sub == 0) {
        #pragma unroll
        for (int j = 0; j < 2; ++j) {
            int t = wn * 64 + j * 32 + l31;
            red[(wm * 128 + t) * 4 + 0] = v1[j];
            red[(wm * 128 + t) * 4 + 1] = v2[j];
            red[(wm * 128 + t) * 4 + 2] = __int_as_float(k1[j]);
        }
    }
    __syncthreads();
    if (tid < 128) {
        float bv1 = red[tid * 4], bv2 = red[tid * 4 + 1];
        int bk = __float_as_int(red[tid * 4 + 2]);
        #pragma unroll
        for (int m = 1; m < 4; ++m) {
            float a1 = red[(m * 128 + tid) * 4], a2 = red[(m * 128 + tid) * 4 + 1];
            int ak = __float_as_int(red[(m * 128 + tid) * 4 + 2]);
            float nv2 = fminf(fminf(bv2, a2), fmaxf(bv1, a1));
            if (a1 < bv1 || (a1 == bv1 && ak < bk)) { bv1 = a1; bk = ak; }
            bv2 = nv2;
        }
        int n = tok0 + tid;
        bestk[n] = bk;
        bdist[n] = bv1;
        if (bv2 - bv1 < MARGIN) rlist[atomicAdd(rcount, 1)] = n;
    }
}

// ================= exact fp32 refine: ILP-batched loads, 8-token batches ==========
__global__ __launch_bounds__(256)
void vq_refine(const float* __restrict__ x, const float* __restrict__ cbT,
               const float* __restrict__ csq, const int* __restrict__ rcount,
               const int* __restrict__ rlist, int* __restrict__ bestk,
               float* __restrict__ bdist) {
    __shared__ float xv[8][256];
    __shared__ float xsq[8];
    __shared__ float wredv[4][8];
    __shared__ int   wredk[4][8];
    const int tid = threadIdx.x;
    const int cnt = min(rcount[0], N_);
    for (int base = blockIdx.x * 8; base < cnt; base += gridDim.x * 8) {
        const int m = min(8, cnt - base);
        __syncthreads();
        for (int j = 0; j < m; ++j) {
            int n = rlist[base + j];
            int b = n >> 10, hw = n & 1023;
            xv[j][tid] = x[(size_t)b * DHW + (size_t)tid * HW_ + hw];
        }
        for (int j = m; j < 8; ++j) xv[j][tid] = 0.f;
        __syncthreads();
        {   // xsq: 8 groups of 32 lanes
            int g = tid >> 5, l = tid & 31;
            float s = 0.f;
            #pragma unroll
            for (int d8 = 0; d8 < 8; ++d8) { float v = xv[g][d8 * 32 + l]; s = fmaf(v, v, s); }
            #pragma unroll
            for (int mm = 1; mm < 32; mm <<= 1) s += __shfl_xor(s, mm, 64);
            if (l == 0) xsq[g] = s;
        }
        __syncthreads();

        float dots[4][8];
        #pragma unroll
        for (int c4 = 0; c4 < 4; ++c4)
            #pragma unroll
            for (int j = 0; j < 8; ++j) dots[c4][j] = 0.f;

        const float* cbase = cbT + tid;
        for (int d0 = 0; d0 < 256; d0 += 8) {
            // token slab -> regs (broadcast LDS reads)
            float xr[8][8];
            #pragma unroll
            for (int j = 0; j < 8; ++j) {
                float4 a = *reinterpret_cast<const float4*>(&xv[j][d0]);
                float4 b = *reinterpret_cast<const float4*>(&xv[j][d0 + 4]);
                xr[j][0] = a.x; xr[j][1] = a.y; xr[j][2] = a.z; xr[j][3] = a.w;
                xr[j][4] = b.x; xr[j][5] = b.y; xr[j][6] = b.z; xr[j][7] = b.w;
            }
            #pragma unroll
            for (int c4 = 0; c4 < 4; ++c4) {
                float cv[8];
                #pragma unroll
                for (int u = 0; u < 8; ++u)
                    cv[u] = cbase[(size_t)(d0 + u) * K_ + c4 * 256];
                #pragma unroll
                for (int u = 0; u < 8; ++u)
                    #pragma unroll
                    for (int j = 0; j < 8; ++j)
                        dots[c4][j] = fmaf(cv[u], xr[j][u], dots[c4][j]);
            }
        }

        float bv[8]; int bk[8];
        #pragma unroll
        for (int j = 0; j < 8; ++j) { bv[j] = 3.4e38f; bk[j] = 0; }
        #pragma unroll
        for (int c4 = 0; c4 < 4; ++c4) {
            const int code = c4 * 256 + tid;
            const float cs = csq[code];
            #pragma unroll
            for (int j = 0; j < 8; ++j) {
                float dist = fmaf(-2.f, dots[c4][j], xsq[j]) + cs;
                if (dist < bv[j]) { bv[j] = dist; bk[j] = code; }
            }
        }
        #pragma unroll
        for (int j = 0; j < 8; ++j) {
            if (j < m) {
                float v = bv[j]; int k = bk[j];
                #pragma unroll
                for (int mm = 1; mm < 64; mm <<= 1) {
                    float ov = __shfl_xor(v, mm, 64);
                    int   ok = __shfl_xor(k, mm, 64);
                    if (ov < v || (ov == v && ok < k)) { v = ov; k = ok; }
                }
                if ((tid & 63) == 0) { wredv[tid >> 6][j] = v; wredk[tid >> 6][j] = k; }
            }
        }
        __syncthreads();
        if (tid < m) {
            float v = wredv[0][tid]; int k = wredk[0][tid];
            #pragma unroll
            for (int q = 1; q < 4; ++q) {
                if (wredv[q][tid] < v || (wredv[q][tid] == v && wredk[q][tid] < k)) {
                    v = wredv[q][tid]; k = wredk[q][tid];
                }
            }
            int n = rlist[base + tid];
            bestk[n] = k;
            bdist[n] = v;
        }
        __syncthreads();
    }
}

// ================= losses from sum of best distances ==========
__global__ __launch_bounds__(1024)
void vq_loss(const float* __restrict__ bdist, float* __restrict__ oloss) {
    __shared__ float r[16];
    float s = 0.f;
    const float4* p = reinterpret_cast<const float4*>(bdist);
    for (int i = threadIdx.x; i < N_ / 4; i += 1024) {
        float4 v = p[i];
        s += (v.x + v.y) + (v.z + v.w);
    }
    #pragma unroll
    for (int mm = 32; mm >= 1; mm >>= 1) s += __shfl_xor(s, mm, 64);
    if ((threadIdx.x & 63) == 0) r[threadIdx.x >> 6] = s;
    __syncthreads();
    if (threadIdx.x == 0) {
        float t = 0.f;
        #pragma unroll
        for (int i = 0; i < 16; ++i) t += r[i];
        t *= (1.0f / 8388608.0f);   // / (N*D)
        oloss[0] = t;
        oloss[1] = t;
    }
}

// ================= gather codewords, write out/idx ==========
__global__ __launch_bounds__(256)
void vq_gather(const float* __restrict__ cb, const int* __restrict__ bestk,
               float* __restrict__ out, float* __restrict__ oidx) {
    const int n0 = blockIdx.x * 64;
    const int tid = threadIdx.x;
    const int j = tid & 63, dg = tid >> 6;
    const int n = n0 + j;
    const int b = n >> 10, hw = n & 1023;
    const int k = bestk[n];
    const float* cw = cb + (size_t)k * D_;
    const size_t basex = (size_t)b * DHW + hw;
    #pragma unroll 4
    for (int d = dg * 64; d < dg * 64 + 64; ++d) {
        out[basex + (size_t)d * HW_] = cw[d];
    }
    if (tid < 64) oidx[n0 + tid] = (float)bestk[n0 + tid];
}

extern "C" void kernel_launch(void* const* d_in, const int* in_sizes, int n_in,
                              void* d_out, int out_size, void* d_ws, size_t ws_size,
                              hipStream_t stream) {
    const float* x  = (const float*)d_in[0];
    const float* cb = (const float*)d_in[1];

    float* out   = (float*)d_out;            // 8388608 floats
    float* oidx  = out + 8388608;            // 32768 floats
    float* oloss = out + 8388608 + 32768;    // 2 floats

    // d_out's first 16 MB reused as scratch for the bf16 token plane
    uint4* xg = (uint4*)d_out;               // [32768][32] uint4

    uint* wsb = (uint*)d_ws;
    uint4*  cbt   = (uint4*)wsb;             // 262144 u32 (1 MB)
    float*  csq   = (float*)(wsb + 262144);  // 1024
    float*  cbT   = (float*)(wsb + 263168);  // 262144 (1 MB, fp32 [d][k])
    int*    bestk = (int*)  (wsb + 525312);  // 32768
    int*    rcount= (int*)  (wsb + 558080);  // 1
    int*    rlist = (int*)  (wsb + 558084);  // 32768
    float*  bdist = (float*)(wsb + 590852);  // 32768

    hipMemsetAsync(rcount, 0, sizeof(int), stream);

    prep_x  <<<512, 256, 0, stream>>>(x, xg);
    prep_cb <<<1024, 256, 0, stream>>>(cb, cbt, csq, cbT);
    vq_main <<<256, 512, 0, stream>>>(xg, cbt, csq, bestk, rcount, rlist, bdist);
    vq_refine<<<256, 256, 0, stream>>>(x, cbT, csq, rcount, rlist, bestk, bdist);
    vq_loss <<<1, 1024, 0, stream>>>(bdist, oloss);
    vq_gather<<<512, 256, 0, stream>>>(cb, bestk, out, oidx);
}

// Round 6
// 130.243 us; speedup vs baseline: 3.2934x; 1.0024x over previous
//
#include <hip/hip_runtime.h>

#define B_   32
#define D_   256
#define HW_  1024
#define N_   32768
#define K_   1024
#define DHW  (D_ * HW_)      // 262144
#define MARGIN 0.3f

typedef __attribute__((ext_vector_type(8)))  short bf16x8;
typedef __attribute__((ext_vector_type(16))) float f32x16;

union FragU { uint4 q; bf16x8 v; };

__device__ inline uint bf16rne(float x) {
    uint ub = __float_as_uint(x);
    return (ub + 0x7fffu + ((ub >> 16) & 1u)) >> 16;
}

// ================= prep_cb: codebook -> hi/lo tiled planes + csq + fp32 transpose ====
__global__ __launch_bounds__(256)
void prep_cb(const float* __restrict__ cb, uint4* __restrict__ cbt,
             float* __restrict__ csq, float* __restrict__ cbT) {
    __shared__ uint sh[256], sl[256];
    __shared__ float rr[4];
    const int k = blockIdx.x, d = threadIdx.x;
    float v = cb[(size_t)k * D_ + d];
    uint hb = bf16rne(v);
    float hf = __uint_as_float(hb << 16);
    uint lb = bf16rne(v - hf);
    sh[d] = hb; sl[d] = lb;
    cbT[(size_t)d * K_ + k] = v;
    float s = v * v;
    #pragma unroll
    for (int off = 32; off >= 1; off >>= 1) s += __shfl_xor(s, off, 64);
    if ((d & 63) == 0) rr[d >> 6] = s;
    __syncthreads();
    if (d == 0) csq[k] = (rr[0] + rr[1]) + (rr[2] + rr[3]);
    if (d < 64) {
        int ch = d >> 3, g = d & 7;
        int p = g >> 2, gg = g & 3;
        const uint* src = p ? sl : sh;
        uint w[4];
        #pragma unroll
        for (int jj = 0; jj < 4; ++jj) {
            int dp = ch * 16 + gg * 4 + jj;
            w[jj] = src[2 * dp] | (src[2 * dp + 1] << 16);
        }
        cbt[(size_t)(ch * 1024 + k) * 8 + g] = make_uint4(w[0], w[1], w[2], w[3]);
    }
}

// ================= main: fused x->bf16 staging + LDS MFMA distances + argmin ==========
// 256 blocks x 512 thr. Block: 128 tokens x 1024 codes. codes=A(rows, hi+lo), tokens=B(cols, hi).
__global__ __launch_bounds__(512)
void vq_main(const float* __restrict__ x, const uint4* __restrict__ cbt,
             const float* __restrict__ csqg, int* __restrict__ bestk,
             int* __restrict__ rcount, int* __restrict__ rlist,
             float* __restrict__ bdist) {
    __shared__ uint4 TkS[4096];        // 64 KB: [token 128][32 slots], slot = g ^ (t&7)
    __shared__ uint4 CbS[2][2048];     // 2x32 KB: [code 256][8 slots], slot = g ^ (c&7)
    __shared__ float csqS[1024];       // 4 KB

    const int tid = threadIdx.x;
    const int lane = tid & 63;
    const int sub = lane >> 5, l31 = lane & 31;
    const int wid = tid >> 6;
    const int wm = wid >> 1, wn = wid & 1;
    const int tok0 = blockIdx.x * 128;
    const int bb = tok0 >> 10, hw0 = tok0 & 1023;

    csqS[tid] = csqg[tid];
    csqS[tid + 512] = csqg[tid + 512];

    // ---- build TkS directly from x (fused prep_x) ----
    {
        const int t = tid & 127;           // token within block
        const int dgrp = tid >> 7;         // 0..3 (wave-uniform)
        const float* xp = x + (size_t)bb * DHW + hw0 + t;
        #pragma unroll
        for (int i = 0; i < 8; ++i) {
            int g = i * 4 + dgrp;          // 0..31, covers d = 8g..8g+7
            float v[8];
            #pragma unroll
            for (int e = 0; e < 8; ++e)
                v[e] = xp[(size_t)(g * 8 + e) * HW_];
            uint w[4];
            #pragma unroll
            for (int jj = 0; jj < 4; ++jj)
                w[jj] = bf16rne(v[2 * jj]) | (bf16rne(v[2 * jj + 1]) << 16);
            TkS[t * 32 + (g ^ (t & 7))] = make_uint4(w[0], w[1], w[2], w[3]);
        }
    }
    asm volatile("s_waitcnt vmcnt(0) lgkmcnt(0)" ::: "memory");
    __syncthreads();

    // ---- code-chunk staging constants ----
    const int s_cl = tid >> 3;               // + it*64
    const int s_g = (tid & 7) ^ (s_cl & 7);  // (it*64) preserves c&7

    // stage chunk 0 into buf 0
    #pragma unroll
    for (int it = 0; it < 4; ++it) {
        int u = it * 512 + tid;
        int cl = it * 64 + s_cl;
        const uint4* src = cbt + (size_t)cl * 8 + s_g;
        __builtin_amdgcn_global_load_lds((const uint*)src, (uint*)&CbS[0][u], 16, 0, 0);
    }

    f32x16 acc[2][2] = {};
    float v1[2] = {3.4e38f, 3.4e38f}, v2[2] = {3.4e38f, 3.4e38f};
    int k1[2] = {0, 0};

    int cur = 0;
    for (int cc = 0; cc < 32; ++cc) {
        asm volatile("s_barrier" ::: "memory");   // B1: all reads of buf[cur^1] done
        if (cc + 1 < 32) {
            const int nct = (cc + 1) >> 3, nch = (cc + 1) & 7;
            #pragma unroll
            for (int it = 0; it < 4; ++it) {
                int u = it * 512 + tid;
                int cl = it * 64 + s_cl;
                const uint4* src = cbt + (size_t)(nch * 1024 + nct * 256 + cl) * 8 + s_g;
                __builtin_amdgcn_global_load_lds((const uint*)src, (uint*)&CbS[cur ^ 1][u], 16, 0, 0);
            }
            asm volatile("s_waitcnt vmcnt(4)" ::: "memory");  // buf[cur] arrived; 4 in flight
        } else {
            asm volatile("s_waitcnt vmcnt(0)" ::: "memory");
        }
        asm volatile("s_barrier" ::: "memory");   // B2: every wave's loads drained

        const int ch = cc & 7;
        #pragma unroll
        for (int ks = 0; ks < 2; ++ks) {
            FragU tf[2], cfh[2], cfl[2];
            #pragma unroll
            for (int j = 0; j < 2; ++j) {
                int t = wn * 64 + j * 32 + l31;
                int g32 = ch * 4 + ks * 2 + sub;
                tf[j].q = TkS[t * 32 + (g32 ^ (t & 7))];
            }
            #pragma unroll
            for (int f = 0; f < 2; ++f) {
                int cl = wm * 64 + f * 32 + l31;
                int gh = ks * 2 + sub;
                int gl = 4 + ks * 2 + sub;
                cfh[f].q = CbS[cur][cl * 8 + (gh ^ (cl & 7))];
                cfl[f].q = CbS[cur][cl * 8 + (gl ^ (cl & 7))];
            }
            // 4 independent hi-MFMAs first, then the dependent lo pass
            #pragma unroll
            for (int f = 0; f < 2; ++f)
                #pragma unroll
                for (int j = 0; j < 2; ++j)
                    acc[f][j] = __builtin_amdgcn_mfma_f32_32x32x16_bf16(cfh[f].v, tf[j].v, acc[f][j], 0, 0, 0);
            #pragma unroll
            for (int f = 0; f < 2; ++f)
                #pragma unroll
                for (int j = 0; j < 2; ++j)
                    acc[f][j] = __builtin_amdgcn_mfma_f32_32x32x16_bf16(cfl[f].v, tf[j].v, acc[f][j], 0, 0, 0);
        }
        cur ^= 1;

        // ---- per-code-tile epilogue: scores + per-lane running top-2 ----
        if ((cc & 7) == 7) {
            const int ct = cc >> 3;
            const int cbase = ct * 256 + wm * 64 + sub * 4;
            #pragma unroll
            for (int f = 0; f < 2; ++f) {
                #pragma unroll
                for (int g8 = 0; g8 < 4; ++g8) {
                    float4 cs4 = *reinterpret_cast<const float4*>(&csqS[cbase + f * 32 + g8 * 8]);
                    const float csa[4] = {cs4.x, cs4.y, cs4.z, cs4.w};
                    #pragma unroll
                    for (int q = 0; q < 4; ++q) {
                        int code = cbase + f * 32 + g8 * 8 + q;
                        int r = g8 * 4 + q;
                        #pragma unroll
                        for (int j = 0; j < 2; ++j) {
                            float s = fmaf(-2.f, acc[f][j][r], csa[q]);
                            bool c = s < v1[j];
                            v2[j] = c ? v1[j] : fminf(v2[j], s);
                            k1[j] = c ? code : k1[j];
                            v1[j] = c ? s : v1[j];
                        }
                    }
                }
            }
            const f32x16 zf = {};
            #pragma unroll
            for (int f = 0; f < 2; ++f)
                #pragma unroll
                for (int j = 0; j < 2; ++j) acc[f][j] = zf;
        }
    }

    // ---- merge sub halves (codes interleaved across sub) ----
    #pragma unroll
    for (int j = 0; j < 2; ++j) {
        float ov1 = __shfl_xor(v1[j], 32, 64);
        float ov2 = __shfl_xor(v2[j], 32, 64);
        int   ok1 = __shfl_xor(k1[j], 32, 64);
        float nv2 = fminf(fminf(v2[j], ov2), fmaxf(v1[j], ov1));
        if (ov1 < v1[j] || (ov1 == v1[j] && ok1 < k1[j])) { v1[j] = ov1; k1[j] = ok1; }
        v2[j] = nv2;
    }
    __syncthreads();
    float* red = (float*)&CbS[0][0];   // alias: [4 wm][128 token][4]
    if (sub == 0) {
        #pragma unroll
        for (int j = 0; j < 2; ++j) {
            int t = wn * 64 + j * 32 + l31;
            red[(wm * 128 + t) * 4 + 0] = v1[j];
            red[(wm * 128 + t) * 4 + 1] = v2[j];
            red[(wm * 128 + t) * 4 + 2] = __int_as_float(k1[j]);
        }
    }
    __syncthreads();
    if (tid < 128) {
        float bv1 = red[tid * 4], bv2 = red[tid * 4 + 1];
        int bk = __float_as_int(red[tid * 4 + 2]);
        #pragma unroll
        for (int m = 1; m < 4; ++m) {
            float a1 = red[(m * 128 + tid) * 4], a2 = red[(m * 128 + tid) * 4 + 1];
            int ak = __float_as_int(red[(m * 128 + tid) * 4 + 2]);
            float nv2 = fminf(fminf(bv2, a2), fmaxf(bv1, a1));
            if (a1 < bv1 || (a1 == bv1 && ak < bk)) { bv1 = a1; bk = ak; }
            bv2 = nv2;
        }
        int n = tok0 + tid;
        bestk[n] = bk;
        bdist[n] = bv1;
        if (bv2 - bv1 < MARGIN) rlist[atomicAdd(rcount, 1)] = n;
    }
}

// ================= exact fp32 refine: ILP-batched loads, 8-token batches ==========
__global__ __launch_bounds__(256)
void vq_refine(const float* __restrict__ x, const float* __restrict__ cbT,
               const float* __restrict__ csq, const int* __restrict__ rcount,
               const int* __restrict__ rlist, int* __restrict__ bestk,
               float* __restrict__ bdist) {
    __shared__ float xv[8][256];
    __shared__ float xsq[8];
    __shared__ float wredv[4][8];
    __shared__ int   wredk[4][8];
    const int tid = threadIdx.x;
    const int cnt = min(rcount[0], N_);
    for (int base = blockIdx.x * 8; base < cnt; base += gridDim.x * 8) {
        const int m = min(8, cnt - base);
        __syncthreads();
        for (int j = 0; j < m; ++j) {
            int n = rlist[base + j];
            int b = n >> 10, hw = n & 1023;
            xv[j][tid] = x[(size_t)b * DHW + (size_t)tid * HW_ + hw];
        }
        for (int j = m; j < 8; ++j) xv[j][tid] = 0.f;
        __syncthreads();
        {   // xsq: 8 groups of 32 lanes
            int g = tid >> 5, l = tid & 31;
            float s = 0.f;
            #pragma unroll
            for (int d8 = 0; d8 < 8; ++d8) { float v = xv[g][d8 * 32 + l]; s = fmaf(v, v, s); }
            #pragma unroll
            for (int mm = 1; mm < 32; mm <<= 1) s += __shfl_xor(s, mm, 64);
            if (l == 0) xsq[g] = s;
        }
        __syncthreads();

        float dots[4][8];
        #pragma unroll
        for (int c4 = 0; c4 < 4; ++c4)
            #pragma unroll
            for (int j = 0; j < 8; ++j) dots[c4][j] = 0.f;

        const float* cbase = cbT + tid;
        for (int d0 = 0; d0 < 256; d0 += 8) {
            float xr[8][8];
            #pragma unroll
            for (int j = 0; j < 8; ++j) {
                float4 a = *reinterpret_cast<const float4*>(&xv[j][d0]);
                float4 b = *reinterpret_cast<const float4*>(&xv[j][d0 + 4]);
                xr[j][0] = a.x; xr[j][1] = a.y; xr[j][2] = a.z; xr[j][3] = a.w;
                xr[j][4] = b.x; xr[j][5] = b.y; xr[j][6] = b.z; xr[j][7] = b.w;
            }
            #pragma unroll
            for (int c4 = 0; c4 < 4; ++c4) {
                float cv[8];
                #pragma unroll
                for (int u = 0; u < 8; ++u)
                    cv[u] = cbase[(size_t)(d0 + u) * K_ + c4 * 256];
                #pragma unroll
                for (int u = 0; u < 8; ++u)
                    #pragma unroll
                    for (int j = 0; j < 8; ++j)
                        dots[c4][j] = fmaf(cv[u], xr[j][u], dots[c4][j]);
            }
        }

        float bv[8]; int bk[8];
        #pragma unroll
        for (int j = 0; j < 8; ++j) { bv[j] = 3.4e38f; bk[j] = 0; }
        #pragma unroll
        for (int c4 = 0; c4 < 4; ++c4) {
            const int code = c4 * 256 + tid;
            const float cs = csq[code];
            #pragma unroll
            for (int j = 0; j < 8; ++j) {
                float dist = fmaf(-2.f, dots[c4][j], xsq[j]) + cs;
                if (dist < bv[j]) { bv[j] = dist; bk[j] = code; }
            }
        }
        #pragma unroll
        for (int j = 0; j < 8; ++j) {
            if (j < m) {
                float v = bv[j]; int k = bk[j];
                #pragma unroll
                for (int mm = 1; mm < 64; mm <<= 1) {
                    float ov = __shfl_xor(v, mm, 64);
                    int   ok = __shfl_xor(k, mm, 64);
                    if (ov < v || (ov == v && ok < k)) { v = ov; k = ok; }
                }
                if ((tid & 63) == 0) { wredv[tid >> 6][j] = v; wredk[tid >> 6][j] = k; }
            }
        }
        __syncthreads();
        if (tid < m) {
            float v = wredv[0][tid]; int k = wredk[0][tid];
            #pragma unroll
            for (int q = 1; q < 4; ++q) {
                if (wredv[q][tid] < v || (wredv[q][tid] == v && wredk[q][tid] < k)) {
                    v = wredv[q][tid]; k = wredk[q][tid];
                }
            }
            int n = rlist[base + tid];
            bestk[n] = k;
            bdist[n] = v;
        }
        __syncthreads();
    }
}

// ================= gather codewords, write out/idx, fused loss ==========
__global__ __launch_bounds__(256)
void vq_gather(const float* __restrict__ cb, const int* __restrict__ bestk,
               const float* __restrict__ bdist, float* __restrict__ out,
               float* __restrict__ oidx, float* __restrict__ oloss) {
    const int n0 = blockIdx.x * 64;
    const int tid = threadIdx.x;
    const int j = tid & 63, dg = tid >> 6;
    const int n = n0 + j;
    const int b = n >> 10, hw = n & 1023;
    const int k = bestk[n];
    const float* cw = cb + (size_t)k * D_;
    const size_t basex = (size_t)b * DHW + hw;
    #pragma unroll 4
    for (int d = dg * 64; d < dg * 64 + 64; ++d) {
        out[basex + (size_t)d * HW_] = cw[d];
    }
    if (tid < 64) {
        oidx[n0 + tid] = (float)bestk[n0 + tid];
        float v = bdist[n0 + tid];
        #pragma unroll
        for (int off = 32; off >= 1; off >>= 1) v += __shfl_xor(v, off, 64);
        if (tid == 0) {
            float t = v * (1.0f / 8388608.0f);   // / (N*D)
            atomicAdd(&oloss[0], t);
            atomicAdd(&oloss[1], t);
        }
    }
}

extern "C" void kernel_launch(void* const* d_in, const int* in_sizes, int n_in,
                              void* d_out, int out_size, void* d_ws, size_t ws_size,
                              hipStream_t stream) {
    const float* x  = (const float*)d_in[0];
    const float* cb = (const float*)d_in[1];

    float* out   = (float*)d_out;            // 8388608 floats
    float* oidx  = out + 8388608;            // 32768 floats
    float* oloss = out + 8388608 + 32768;    // 2 floats

    uint* wsb = (uint*)d_ws;
    uint4*  cbt   = (uint4*)wsb;             // 262144 u32 (1 MB)
    float*  csq   = (float*)(wsb + 262144);  // 1024
    float*  cbT   = (float*)(wsb + 263168);  // 262144 (1 MB, fp32 [d][k])
    int*    bestk = (int*)  (wsb + 525312);  // 32768
    int*    rcount= (int*)  (wsb + 558080);  // 1
    int*    rlist = (int*)  (wsb + 558084);  // 32768
    float*  bdist = (float*)(wsb + 590852);  // 32768

    hipMemsetAsync(rcount, 0, sizeof(int), stream);
    hipMemsetAsync(oloss, 0, 2 * sizeof(float), stream);

    prep_cb <<<1024, 256, 0, stream>>>(cb, cbt, csq, cbT);
    vq_main <<<256, 512, 0, stream>>>(x, cbt, csq, bestk, rcount, rlist, bdist);
    vq_refine<<<256, 256, 0, stream>>>(x, cbT, csq, rcount, rlist, bestk, bdist);
    vq_gather<<<512, 256, 0, stream>>>(cb, bestk, bdist, out, oidx, oloss);
}